// Round 13
// baseline (228.918 us; speedup 1.0000x reference)
//
#include <hip/hip_runtime.h>
#include <hip/hip_bf16.h>
#include <math.h>

#define T_FRAMES 4
#define C 128
#define H 192
#define W 192
#define H4 48
#define W4 48
#define FEAT_LEN 2048   // C*S*S
#define FEAT_NUM 2304   // H4*W4
#define HW (H*W)        // 36864
#define NCH 384         // 3*C (conv in-channels)
#define KTOT 3456       // 9*NCH
#define NSTEP 54        // 6 chunks * 9 taps, 64 k each
#define PPX 194         // padded rows/cols
#define NBW 72          // bitmap words per frame = FEAT_NUM/32

typedef __bf16 bf16x8 __attribute__((ext_vector_type(8)));
typedef float f32x4 __attribute__((ext_vector_type(4)));

// direct global->LDS async copy, 16 bytes per lane.
__device__ __forceinline__ void gl16(const void* gp, void* ldsbase) {
    __builtin_amdgcn_global_load_lds(
        (const __attribute__((address_space(1))) void*)gp,
        (__attribute__((address_space(3))) void*)ldsbase, 16, 0, 0);
}

// ---- shared sampling helper: must be bit-identical everywhere ----
__device__ __forceinline__ void sample_loc(const float* __restrict__ loc, int k, int p,
                                           int& iy, int& ix, int& valid) {
    float gfx = loc[(2*k+0)*FEAT_NUM + p];
    float gfy = loc[(2*k+1)*FEAT_NUM + p];
    float gx = 2.0f*gfx/47.0f - 1.0f;
    float gy = 2.0f*gfy/47.0f - 1.0f;
    float fx = (gx + 1.0f)*0.5f*47.0f;
    float fy = (gy + 1.0f)*0.5f*47.0f;
    int jx = (int)rintf(fx);   // round half to even == jnp.round
    int jy = (int)rintf(fy);
    valid = (jx >= 0 && jx < W4 && jy >= 0 && jy < H4) ? 1 : 0;
    ix = min(max(jx, 0), W4-1);
    iy = min(max(jy, 0), H4-1);
}

// ---- bitmap of sampled (k,sp) tokens ----
__global__ __launch_bounds__(256) void k_needA(const float* __restrict__ loc,
                                               uint* __restrict__ needA) {
    int p = blockIdx.x*256 + threadIdx.x;
    if (p >= FEAT_NUM) return;
#pragma unroll
    for (int k = 0; k < T_FRAMES; ++k) {
        int iy, ix, valid;
        sample_loc(loc, k, p, iy, ix, valid);
        int sp = iy*W4 + ix;
        atomicOr(&needA[k*NBW + (sp >> 5)], 1u << (sp & 31));
    }
}

// ---- transpose idx set: [k][f][p] -> [k][p][f] (fp32), round-11 shape ----
// 64x64 tile, float4 reads, write-skip via needA. NOTE (r12): transposes are
// at a ~3.6 TB/s structural floor — burst-length retile was neutral; stop
// tuning this shape.
__global__ __launch_bounds__(256) void k_tr(const float* __restrict__ src,
                                            float* __restrict__ dst,
                                            const uint* __restrict__ needA) {
    __shared__ float lds[64*65];
    int p0 = blockIdx.x*64, f0 = blockIdx.y*64, k = blockIdx.z;
    const float* s = src + (size_t)k*FEAT_LEN*FEAT_NUM;
    float* d = dst + (size_t)k*FEAT_NUM*FEAT_LEN;
    int tid = threadIdx.x;
    int pq = (tid & 15)*4, fr = tid >> 4;       // read: float4 along p
#pragma unroll
    for (int i = 0; i < 4; ++i) {
        int fl = fr + i*16;
        float4 v = *(const float4*)&s[(size_t)(f0+fl)*FEAT_NUM + p0 + pq];
        lds[fl*65 + pq + 0] = v.x;
        lds[fl*65 + pq + 1] = v.y;
        lds[fl*65 + pq + 2] = v.z;
        lds[fl*65 + pq + 3] = v.w;
    }
    __syncthreads();
    int f4 = (tid & 15)*4, pb = tid >> 4;       // write: lanes contiguous in f
#pragma unroll
    for (int i = 0; i < 4; ++i) {
        int pl2 = pb + i*16;
        int sp = p0 + pl2;
        if (!(needA[k*NBW + (sp >> 5)] & (1u << (sp & 31)))) continue;
        float4 v = { lds[(f4+0)*65 + pl2], lds[(f4+1)*65 + pl2],
                     lds[(f4+2)*65 + pl2], lds[(f4+3)*65 + pl2] };
        *(float4*)&d[(size_t)sp*FEAT_LEN + f0 + f4] = v;
    }
}

// ---- transpose sparse sets: [k][f][p] fp32 -> [set][k][p][f] bf16 ----
// round-11 shape; write-skip via needB.
__global__ __launch_bounds__(256) void k_trs(const float* __restrict__ s1,
                                             const float* __restrict__ s2,
                                             const float* __restrict__ s3,
                                             ushort* __restrict__ spT,
                                             const uint* __restrict__ needB) {
    __shared__ float lds[64*65];
    int p0 = blockIdx.x*64, f0 = blockIdx.y*64;
    int z = blockIdx.z;                          // set*4 + k
    int set = z >> 2, k = z & 3;
    const float* src = (set == 0) ? s1 : ((set == 1) ? s2 : s3);
    const float* s = src + (size_t)k*FEAT_LEN*FEAT_NUM;
    int tid = threadIdx.x;
    int pq = (tid & 15)*4, fr = tid >> 4;       // read: float4 along p
#pragma unroll
    for (int i = 0; i < 4; ++i) {
        int fl = fr + i*16;
        float4 v = *(const float4*)&s[(size_t)(f0+fl)*FEAT_NUM + p0 + pq];
        lds[fl*65 + pq + 0] = v.x;
        lds[fl*65 + pq + 1] = v.y;
        lds[fl*65 + pq + 2] = v.z;
        lds[fl*65 + pq + 3] = v.w;
    }
    __syncthreads();
    int fo = (tid & 7)*8, pr = tid >> 3;        // write: lanes contiguous in f
#pragma unroll
    for (int i = 0; i < 2; ++i) {
        int row = pr + i*32;
        int sp = p0 + row;
        if (!(needB[k*NBW + (sp >> 5)] & (1u << (sp & 31)))) continue;
        ushort vv[8];
#pragma unroll
        for (int j = 0; j < 8; ++j) {
            __hip_bfloat16 b = __float2bfloat16(lds[(fo+j)*65 + row]);
            vv[j] = *(ushort*)&b;
        }
        uint4 pk;
        pk.x = (uint)vv[0] | ((uint)vv[1] << 16);
        pk.y = (uint)vv[2] | ((uint)vv[3] << 16);
        pk.z = (uint)vv[4] | ((uint)vv[5] << 16);
        pk.w = (uint)vv[6] | ((uint)vv[7] << 16);
        *(uint4*)(spT + ((size_t)z*FEAT_NUM + sp)*FEAT_LEN + f0 + fo) = pk;
    }
}

// ---- fast gather: contiguous token reads from spT, coalesced NHWC writes ----
__global__ __launch_bounds__(256) void k_gather2(const ushort* __restrict__ spT,
                                                 const float* __restrict__ loc,
                                                 const int* __restrict__ corr_index,
                                                 ushort* __restrict__ cat) {
    __shared__ ushort tok[3*FEAT_LEN];           // 12 KB
    int p = blockIdx.x;
    int y4 = p / W4, x4 = p - y4*W4;
    int tid = threadIdx.x;
    int k = corr_index[p];
    int iy, ix, valid;
    sample_loc(loc, k, p, iy, ix, valid);
    int sp = iy*W4 + ix;

#pragma unroll
    for (int j = 0; j < 3; ++j) {
        int idx = j*256 + tid;
        int set = idx >> 8, off = (idx & 255)*8;
        uint4 v = {0u,0u,0u,0u};
        if (valid)
            v = *(const uint4*)(spT + ((size_t)(set*4 + k)*FEAT_NUM + sp)*FEAT_LEN + off);
        *(uint4*)(tok + set*FEAT_LEN + off) = v;
    }
    __syncthreads();

#pragma unroll
    for (int j = 0; j < 3; ++j) {
        int idx = j*256 + tid;
        int px16 = idx / 48, oct = idx - px16*48;
        int ky = px16 >> 2, kx = px16 & 3;
        int y = y4*4 + ky, x = x4*4 + kx;
        int set = oct >> 4, c0 = (oct & 15)*8;
        int sub = (ky << 2) + kx;
        ushort vv[8];
#pragma unroll
        for (int e = 0; e < 8; ++e) vv[e] = tok[set*FEAT_LEN + ((c0 + e) << 4) + sub];
        uint4 pk;
        pk.x = (uint)vv[0] | ((uint)vv[1] << 16);
        pk.y = (uint)vv[2] | ((uint)vv[3] << 16);
        pk.z = (uint)vv[4] | ((uint)vv[5] << 16);
        pk.w = (uint)vv[6] | ((uint)vv[7] << 16);
        *(uint4*)(cat + ((size_t)(y+1)*PPX + (x+1))*NCH + set*128 + c0) = pk;
    }
}

// ---- fast correlation + needB bitmap build ----
__global__ __launch_bounds__(256) void k_corr2(const float* __restrict__ curr,
                                               const float* __restrict__ idxT,
                                               const float* __restrict__ loc,
                                               int* __restrict__ corr_index,
                                               float* __restrict__ corr_soft,
                                               uint* __restrict__ needB) {
    int p = blockIdx.x;
    int y4 = p / W4, x4 = p - y4*W4;
    int tid = threadIdx.x;

    int iy[T_FRAMES], ix[T_FRAMES], valid[T_FRAMES];
    const float* tok[T_FRAMES];
#pragma unroll
    for (int k = 0; k < T_FRAMES; ++k) {
        sample_loc(loc, k, p, iy[k], ix[k], valid[k]);
        tok[k] = idxT + ((size_t)k*FEAT_NUM + iy[k]*W4 + ix[k])*FEAT_LEN;
    }

    float ss_cf = 0.f;
    float dotk[T_FRAMES] = {0.f,0.f,0.f,0.f};
    float ssk[T_FRAMES]  = {0.f,0.f,0.f,0.f};
    int ybase = y4*4, xbase = x4*4;

#pragma unroll
    for (int it = 0; it < 2; ++it) {
        int f4 = (tid + it*256)*4;
        int cc = f4 >> 4, kh = (f4 >> 2) & 3;
        float4 cf = *(const float4*)&curr[cc*HW + (ybase+kh)*W + xbase];
        ss_cf += cf.x*cf.x + cf.y*cf.y + cf.z*cf.z + cf.w*cf.w;
#pragma unroll
        for (int k = 0; k < T_FRAMES; ++k) {
            if (valid[k]) {
                float4 v = *(const float4*)&tok[k][f4];
                dotk[k] += cf.x*v.x + cf.y*v.y + cf.z*v.z + cf.w*v.w;
                ssk[k]  += v.x*v.x + v.y*v.y + v.z*v.z + v.w*v.w;
            }
        }
    }

    float vals[9] = {ss_cf, dotk[0],dotk[1],dotk[2],dotk[3], ssk[0],ssk[1],ssk[2],ssk[3]};
#pragma unroll
    for (int j = 0; j < 9; ++j) {
        float v = vals[j];
#pragma unroll
        for (int off = 32; off > 0; off >>= 1) v += __shfl_xor(v, off, 64);
        vals[j] = v;
    }
    __shared__ float red[4][9];
    int wave = tid >> 6, lane = tid & 63;
    if (lane == 0) {
#pragma unroll
        for (int j = 0; j < 9; ++j) red[wave][j] = vals[j];
    }
    __syncthreads();
    if (tid == 0) {
        float tot[9];
#pragma unroll
        for (int j = 0; j < 9; ++j) tot[j] = red[0][j]+red[1][j]+red[2][j]+red[3][j];
        float ncf = fmaxf(sqrtf(tot[0]), 1e-12f);
        float best = -1e30f; int bestk = 0;
#pragma unroll
        for (int k = 0; k < T_FRAMES; ++k) {
            float nk = fmaxf(sqrtf(tot[5+k]), 1e-12f);
            float m = tot[1+k] / (nk * ncf);
            if (m > best) { best = m; bestk = k; }   // strict > == first-max
        }
        corr_index[p] = bestk;
        corr_soft[p]  = best;
        int spb = iy[bestk]*W4 + ix[bestk];
        atomicOr(&needB[bestk*NBW + (spb >> 5)], 1u << (spb & 31));
    }
}

// ---- fallback correlation (strided reads) if ws too small for idxT ----
__global__ __launch_bounds__(256) void k_corr(const float* __restrict__ curr,
                                              const float* __restrict__ idxf,
                                              const float* __restrict__ loc,
                                              int* __restrict__ corr_index,
                                              float* __restrict__ corr_soft) {
    int p = blockIdx.x;
    int y4 = p / W4, x4 = p - y4*W4;
    int tid = threadIdx.x;

    int iy[T_FRAMES], ix[T_FRAMES], valid[T_FRAMES];
#pragma unroll
    for (int k = 0; k < T_FRAMES; ++k) sample_loc(loc, k, p, iy[k], ix[k], valid[k]);

    float ss_cf = 0.f;
    float dotk[T_FRAMES] = {0.f,0.f,0.f,0.f};
    float ssk[T_FRAMES]  = {0.f,0.f,0.f,0.f};

    int ybase = y4*4, xbase = x4*4;
    for (int f = tid; f < FEAT_LEN; f += 256) {
        int cc = f >> 4;
        int kh = (f >> 2) & 3;
        int kw = f & 3;
        float cf = curr[cc*HW + (ybase+kh)*W + (xbase+kw)];
        ss_cf += cf*cf;
#pragma unroll
        for (int k = 0; k < T_FRAMES; ++k) {
            float v = 0.f;
            if (valid[k]) v = idxf[(k*FEAT_LEN + f)*FEAT_NUM + iy[k]*W4 + ix[k]];
            dotk[k] += cf*v;
            ssk[k]  += v*v;
        }
    }

    float vals[9] = {ss_cf, dotk[0],dotk[1],dotk[2],dotk[3], ssk[0],ssk[1],ssk[2],ssk[3]};
#pragma unroll
    for (int j = 0; j < 9; ++j) {
        float v = vals[j];
#pragma unroll
        for (int off = 32; off > 0; off >>= 1) v += __shfl_xor(v, off, 64);
        vals[j] = v;
    }
    __shared__ float red[4][9];
    int wave = tid >> 6, lane = tid & 63;
    if (lane == 0) {
#pragma unroll
        for (int j = 0; j < 9; ++j) red[wave][j] = vals[j];
    }
    __syncthreads();
    if (tid == 0) {
        float tot[9];
#pragma unroll
        for (int j = 0; j < 9; ++j) tot[j] = red[0][j]+red[1][j]+red[2][j]+red[3][j];
        float ncf = fmaxf(sqrtf(tot[0]), 1e-12f);
        float best = -1e30f; int bestk = 0;
#pragma unroll
        for (int k = 0; k < T_FRAMES; ++k) {
            float nk = fmaxf(sqrtf(tot[5+k]), 1e-12f);
            float m = tot[1+k] / (nk * ncf);
            if (m > best) { best = m; bestk = k; }
        }
        corr_index[p] = bestk;
        corr_soft[p]  = best;
    }
}

// ---- weights fp32 OIHW -> bf16 MFMA-fragment order ----
// wt2[(((step*2 + kk)*8 + g)*64 + lane)*8 + e]
__global__ __launch_bounds__(256) void k_wconv(const float* __restrict__ w,
                                               ushort* __restrict__ wt2) {
    int gid = blockIdx.x*256 + threadIdx.x;
    if (gid >= 128*KTOT) return;
    int e  = gid & 7;
    int l  = (gid >> 3) & 63;
    int g  = (gid >> 9) & 7;
    int kkstep = gid >> 12;          // 0..107
    int kk = kkstep & 1, step = kkstep >> 1;
    int lx = l & 15, lg = l >> 4;
    int col = g*16 + lx;
    int chunk = step / 9, tap = step - chunk*9;
    int ci = chunk*64 + kk*32 + lg*8 + e;
    __hip_bfloat16 b = __float2bfloat16(w[(col*NCH + ci)*9 + tap]);
    wt2[gid] = *(ushort*)&b;
}

// ---- zero the 1-px border of padded NHWC cat ----
__global__ __launch_bounds__(256) void k_border(ushort* __restrict__ cat) {
    int gid = blockIdx.x*256 + threadIdx.x;
    if (gid >= 772*48) return;
    int oct = gid % 48, bp = gid / 48;
    int ypad, xpad;
    if (bp < 194)      { ypad = 0;        xpad = bp; }
    else if (bp < 388) { ypad = 193;      xpad = bp - 194; }
    else if (bp < 580) { ypad = bp - 387; xpad = 0; }
    else               { ypad = bp - 579; xpad = 193; }
    uint4 z = {0u,0u,0u,0u};
    *(uint4*)(cat + (ypad*PPX + xpad)*NCH + oct*8) = z;
}

// ---- fallback gather (strided reads) ----
__global__ __launch_bounds__(256) void k_gather(const float* __restrict__ s1,
                                                const float* __restrict__ s2,
                                                const float* __restrict__ s3,
                                                const float* __restrict__ loc,
                                                const int* __restrict__ corr_index,
                                                ushort* __restrict__ cat) {
    int gid = blockIdx.x*256 + threadIdx.x;
    if (gid >= HW*48) return;
    int oct = gid % 48, px = gid / 48;
    int x = px % W, y = px / W;
    int p = (y >> 2)*W4 + (x >> 2);
    int k = corr_index[p];
    int iy, ix, valid;
    sample_loc(loc, k, p, iy, ix, valid);
    int set = oct >> 4;
    int c0  = (oct & 15) * 8;
    int sub = ((y & 3) << 2) + (x & 3);
    ushort v[8];
#pragma unroll
    for (int e = 0; e < 8; ++e) v[e] = 0;
    if (valid) {
        const float* src = (set == 0) ? s1 : ((set == 1) ? s2 : s3);
        const float* sp = src + (size_t)k*FEAT_LEN*FEAT_NUM + iy*W4 + ix;
#pragma unroll
        for (int e = 0; e < 8; ++e) {
            int f = ((c0 + e) << 4) + sub;
            __hip_bfloat16 b = __float2bfloat16(sp[(size_t)f*FEAT_NUM]);
            v[e] = *(ushort*)&b;
        }
    }
    uint4 pk;
    pk.x = (uint)v[0] | ((uint)v[1] << 16);
    pk.y = (uint)v[2] | ((uint)v[3] << 16);
    pk.z = (uint)v[4] | ((uint)v[5] << 16);
    pk.w = (uint)v[6] | ((uint)v[7] << 16);
    *(uint4*)(cat + ((y+1)*PPX + (x+1))*NCH + oct*8) = pk;
}

// ---- MFMA implicit-GEMM conv 3x3 384->128: 8-wave retry with coalesced W ----
// Round-7's 8-wave geometry regressed due to 16-way-divergent W loads; wt2
// fragment ordering (round 8) removed that confound. Same 64px x 128co block
// tile, grid 576, same X staging; wave = (pg 0..1, cg 0..3) owns 32px x 32co.
// Waves/CU 9 -> 16: doubles latency hiding on the W-load + ds_read chain.
// (256,4) VGPR-cap lesson (round 9) noted: (512,2) caps at 128 VGPR, live
// set ~70 -> no spill.
__global__ __launch_bounds__(512, 2) void k_conv2(const ushort* __restrict__ cat,
                                                  const ushort* __restrict__ wt2,
                                                  const float* __restrict__ bias,
                                                  const float* __restrict__ corr_soft,
                                                  const float* __restrict__ anchor,
                                                  float* __restrict__ out) {
    __shared__ char smX[2][136*128];   // [rc=r*34+xp][64 ci * 2B], swizzled

    int tx = blockIdx.x, ty = blockIdx.y;       // 6 x 96
    int tid = threadIdx.x;
    int wave = tid >> 6, l = tid & 63;
    int lx = l & 15, lg = l >> 4;
    int pg = wave >> 2;                         // y-row group 0..1
    int cg = wave & 3;                          // co group 0..3 (32 co)
    int co0 = cg * 32;

    // stage X[chunk] into smX[b]: 1088 x 16B = 2 per thread + wave-0 tail
    auto stageX = [&](int chunk, int b) {
        char* xb = (char*)smX[b];
#pragma unroll
        for (int q = 0; q < 2; ++q) {
            int idx = tid + q*512;
            int rc = idx >> 3, oct = idx & 7;
            int r = rc / 34, xp = rc - r*34;
            int octp = oct ^ (xp & 7);          // pre-swizzle source (rule #21)
            const ushort* gp = cat + ((size_t)(ty*2 + r)*PPX + (tx*32 + xp))*NCH
                               + chunk*64 + octp*8;
            gl16(gp, xb + (q*512 + wave*64)*16);
        }
        if (wave == 0) {                        // idx 1024..1087 (rc 128..135, r=3)
            int idx = 1024 + l;
            int rc = idx >> 3, oct = idx & 7;
            int xp = rc - 102;                  // r = 3
            int octp = oct ^ (xp & 7);
            const ushort* gp = cat + ((size_t)(ty*2 + 3)*PPX + (tx*32 + xp))*NCH
                               + chunk*64 + octp*8;
            gl16(gp, xb + 1024*16);
        }
    };

    f32x4 acc[2][2];
#pragma unroll
    for (int mf = 0; mf < 2; ++mf)
#pragma unroll
        for (int nf = 0; nf < 2; ++nf) acc[mf][nf] = (f32x4){0.f,0.f,0.f,0.f};

    // fragment-ordered W bases: g = cg*2 + mf (pg-pair waves share -> L1 hit)
    const ushort* wfb[2];
#pragma unroll
    for (int mf = 0; mf < 2; ++mf)
        wfb[mf] = wt2 + ((cg*2 + mf)*64 + l)*8;

    stageX(0, 0);
    __syncthreads();

    for (int chunk = 0; chunk < 6; ++chunk) {
        if (chunk < 5) stageX(chunk+1, (chunk+1) & 1);   // overlaps 9-tap compute
        const char* Xb = smX[chunk & 1];
#pragma unroll
        for (int tap = 0; tap < 9; ++tap) {
            const int step = chunk*9 + tap;
            const int dy = tap/3 - 1, dx = tap%3 - 1;
            // W fragments: ONE coalesced 1KB load each
            bf16x8 wf[2][2];
#pragma unroll
            for (int mf = 0; mf < 2; ++mf)
#pragma unroll
                for (int kk = 0; kk < 2; ++kk)
                    wf[mf][kk] = *(const bf16x8*)(wfb[mf] + (size_t)(step*2 + kk)*4096);
            int xrc[2], xsw[2];
#pragma unroll
            for (int nf = 0; nf < 2; ++nf) {
                int xp2 = nf*16 + lx + dx + 1;
                xrc[nf] = (pg + dy + 1)*34 + xp2;
                xsw[nf] = (xp2 & 7) << 4;
            }
#pragma unroll
            for (int kk = 0; kk < 2; ++kk) {
                int kb = kk*64 + lg*16;
                bf16x8 xf[2];
#pragma unroll
                for (int nf = 0; nf < 2; ++nf)
                    xf[nf] = *(const bf16x8*)(Xb + xrc[nf]*128 + (kb ^ xsw[nf]));
#pragma unroll
                for (int mf = 0; mf < 2; ++mf)
#pragma unroll
                    for (int nf = 0; nf < 2; ++nf)
                        acc[mf][nf] = __builtin_amdgcn_mfma_f32_16x16x32_bf16(
                            wf[mf][kk], xf[nf], acc[mf][nf], 0, 0, 0);
            }
        }
        __syncthreads();   // next-chunk X ready; buffer safe to overwrite
    }

    // epilogue: out = (acc + bias)*corr_soft + anchor
    int y = ty*2 + pg;
    float cs[2]; int pixo[2];
#pragma unroll
    for (int nf = 0; nf < 2; ++nf) {
        int x = tx*32 + nf*16 + lx;
        cs[nf] = corr_soft[(ty >> 1)*W4 + (x >> 2)];
        pixo[nf] = y*W + x;
    }
#pragma unroll
    for (int mf = 0; mf < 2; ++mf) {
#pragma unroll
        for (int j = 0; j < 4; ++j) {
            int co = co0 + mf*16 + lg*4 + j;
            float b = bias[co];
#pragma unroll
            for (int nf = 0; nf < 2; ++nf) {
                int o = co*HW + pixo[nf];
                out[o] = (acc[mf][nf][j] + b)*cs[nf] + anchor[o];
            }
        }
    }
}

extern "C" void kernel_launch(void* const* d_in, const int* in_sizes, int n_in,
                              void* d_out, int out_size, void* d_ws, size_t ws_size,
                              hipStream_t stream) {
    const float* curr   = (const float*)d_in[0];
    const float* idxf   = (const float*)d_in[1];
    const float* anchor = (const float*)d_in[2];
    const float* s1     = (const float*)d_in[3];
    const float* s2     = (const float*)d_in[4];
    const float* s3     = (const float*)d_in[5];
    const float* loc    = (const float*)d_in[6];
    const float* wgt    = (const float*)d_in[7];
    const float* bias   = (const float*)d_in[8];
    float* out = (float*)d_out;

    char* ws = (char*)d_ws;
    int*    corr_index = (int*)ws;                   // 2304 i32
    uint*   needA      = (uint*)(ws + 12288);        // 4*72 words
    uint*   needB      = (uint*)(ws + 13696);        // 4*72 words
    float*  corr_soft  = (float*)(ws + 16384);       // 2304 f32
    ushort* wt2        = (ushort*)(ws + 32768);      // 884,736 B
    ushort* cat        = (ushort*)(ws + 917504);     // 28,912,128 B
    char*   big        = ws + 917504 + 28912128;     // offset 29,829,632
    float*  idxT       = (float*)big;
    ushort* spT        = (ushort*)big;
    const size_t SPT_BYTES  = (size_t)3*T_FRAMES*FEAT_NUM*FEAT_LEN*2;  // 113,246,208
    const size_t IDXT_BYTES = (size_t)T_FRAMES*FEAT_NUM*FEAT_LEN*4;    //  75,497,472
    const size_t NEED_A = 29829632 + (SPT_BYTES > IDXT_BYTES ? SPT_BYTES : IDXT_BYTES);
    const size_t NEED_B = 917504 + IDXT_BYTES;

    if (ws_size >= NEED_A) {
        hipMemsetAsync(ws + 12288, 0, 2560, stream);   // zero needA + needB
        hipLaunchKernelGGL(k_needA, dim3(9), dim3(256), 0, stream, loc, needA);
        hipLaunchKernelGGL(k_tr, dim3(36, 32, 4), dim3(256), 0, stream, idxf, idxT, needA);
        hipLaunchKernelGGL(k_corr2, dim3(FEAT_NUM), dim3(256), 0, stream,
                           curr, idxT, loc, corr_index, corr_soft, needB);
        hipLaunchKernelGGL(k_wconv, dim3((128*KTOT + 255)/256), dim3(256), 0, stream, wgt, wt2);
        hipLaunchKernelGGL(k_border, dim3((772*48 + 255)/256), dim3(256), 0, stream, cat);
        hipLaunchKernelGGL(k_trs, dim3(36, 32, 12), dim3(256), 0, stream,
                           s1, s2, s3, spT, needB);
        hipLaunchKernelGGL(k_gather2, dim3(FEAT_NUM), dim3(256), 0, stream,
                           spT, loc, corr_index, cat);
    } else {
        float*  idxT_b = (float*)(ws + 917504);
        ushort* cat_b  = (ushort*)(ws + 917504);
        if (ws_size >= NEED_B) {
            hipMemsetAsync(ws + 12288, 0, 2560, stream);
            hipLaunchKernelGGL(k_needA, dim3(9), dim3(256), 0, stream, loc, needA);
            hipLaunchKernelGGL(k_tr, dim3(36, 32, 4), dim3(256), 0, stream, idxf, idxT_b, needA);
            hipLaunchKernelGGL(k_corr2, dim3(FEAT_NUM), dim3(256), 0, stream,
                               curr, idxT_b, loc, corr_index, corr_soft, needB);
        } else {
            hipLaunchKernelGGL(k_corr, dim3(FEAT_NUM), dim3(256), 0, stream,
                               curr, idxf, loc, corr_index, corr_soft);
        }
        hipLaunchKernelGGL(k_wconv, dim3((128*KTOT + 255)/256), dim3(256), 0, stream, wgt, wt2);
        hipLaunchKernelGGL(k_border, dim3((772*48 + 255)/256), dim3(256), 0, stream, cat_b);
        hipLaunchKernelGGL(k_gather, dim3((HW*48 + 255)/256), dim3(256), 0, stream,
                           s1, s2, s3, loc, corr_index, cat_b);
        hipLaunchKernelGGL(k_conv2, dim3(6, 96), dim3(512), 0, stream,
                           cat_b, wt2, bias, corr_soft, anchor, out);
        return;
    }
    hipLaunchKernelGGL(k_conv2, dim3(6, 96), dim3(512), 0, stream,
                       cat, wt2, bias, corr_soft, anchor, out);
}

// Round 14
// 201.113 us; speedup vs baseline: 1.1383x; 1.1383x over previous
//
#include <hip/hip_runtime.h>
#include <hip/hip_bf16.h>
#include <math.h>

#define T_FRAMES 4
#define C 128
#define H 192
#define W 192
#define H4 48
#define W4 48
#define FEAT_LEN 2048   // C*S*S
#define FEAT_NUM 2304   // H4*W4
#define HW (H*W)        // 36864
#define NCH 384         // 3*C (conv in-channels)
#define KTOT 3456       // 9*NCH
#define NSTEP 54        // 6 chunks * 9 taps, 64 k each
#define PPX 194         // padded rows/cols

typedef __bf16 bf16x8 __attribute__((ext_vector_type(8)));
typedef float f32x4 __attribute__((ext_vector_type(4)));

// direct global->LDS async copy, 16 bytes per lane.
__device__ __forceinline__ void gl16(const void* gp, void* ldsbase) {
    __builtin_amdgcn_global_load_lds(
        (const __attribute__((address_space(1))) void*)gp,
        (__attribute__((address_space(3))) void*)ldsbase, 16, 0, 0);
}

// ---- shared sampling helper: must be bit-identical everywhere ----
__device__ __forceinline__ void sample_loc(const float* __restrict__ loc, int k, int p,
                                           int& iy, int& ix, int& valid) {
    float gfx = loc[(2*k+0)*FEAT_NUM + p];
    float gfy = loc[(2*k+1)*FEAT_NUM + p];
    float gx = 2.0f*gfx/47.0f - 1.0f;
    float gy = 2.0f*gfy/47.0f - 1.0f;
    float fx = (gx + 1.0f)*0.5f*47.0f;
    float fy = (gy + 1.0f)*0.5f*47.0f;
    int jx = (int)rintf(fx);   // round half to even == jnp.round
    int jy = (int)rintf(fy);
    valid = (jx >= 0 && jx < W4 && jy >= 0 && jy < H4) ? 1 : 0;
    ix = min(max(jx, 0), W4-1);
    iy = min(max(jy, 0), H4-1);
}

// ---- transpose idx set: [k][f][p] -> [k][p][f] (fp32), float4 reads ----
// NOTE (r10-r12): this family of kernels sits at a ~3.6 TB/s mixed-path
// ceiling — burst-length retile (r12) and write-skip (r11) were both neutral.
__global__ __launch_bounds__(256) void k_tr(const float* __restrict__ src,
                                            float* __restrict__ dst) {
    __shared__ float lds[64*65];
    int p0 = blockIdx.x*64, f0 = blockIdx.y*64, k = blockIdx.z;
    const float* s = src + (size_t)k*FEAT_LEN*FEAT_NUM;
    float* d = dst + (size_t)k*FEAT_NUM*FEAT_LEN;
    int tid = threadIdx.x;
    int pq = (tid & 15)*4, fr = tid >> 4;       // read: float4 along p
#pragma unroll
    for (int i = 0; i < 4; ++i) {
        int fl = fr + i*16;
        float4 v = *(const float4*)&s[(size_t)(f0+fl)*FEAT_NUM + p0 + pq];
        lds[fl*65 + pq + 0] = v.x;
        lds[fl*65 + pq + 1] = v.y;
        lds[fl*65 + pq + 2] = v.z;
        lds[fl*65 + pq + 3] = v.w;
    }
    __syncthreads();
    int f4 = (tid & 15)*4, pb = tid >> 4;       // write: lanes contiguous in f
#pragma unroll
    for (int i = 0; i < 4; ++i) {
        int pl2 = pb + i*16;
        float4 v = { lds[(f4+0)*65 + pl2], lds[(f4+1)*65 + pl2],
                     lds[(f4+2)*65 + pl2], lds[(f4+3)*65 + pl2] };
        *(float4*)&d[(size_t)(p0+pl2)*FEAT_LEN + f0 + f4] = v;
    }
}

// ---- transpose sparse sets: [k][f][p] fp32 -> [set][k][p][f] bf16 ----
__global__ __launch_bounds__(256) void k_trs(const float* __restrict__ s1,
                                             const float* __restrict__ s2,
                                             const float* __restrict__ s3,
                                             ushort* __restrict__ spT) {
    __shared__ float lds[64*65];
    int p0 = blockIdx.x*64, f0 = blockIdx.y*64;
    int z = blockIdx.z;                          // set*4 + k
    int set = z >> 2, k = z & 3;
    const float* src = (set == 0) ? s1 : ((set == 1) ? s2 : s3);
    const float* s = src + (size_t)k*FEAT_LEN*FEAT_NUM;
    int tid = threadIdx.x;
    int pq = (tid & 15)*4, fr = tid >> 4;       // read: float4 along p
#pragma unroll
    for (int i = 0; i < 4; ++i) {
        int fl = fr + i*16;
        float4 v = *(const float4*)&s[(size_t)(f0+fl)*FEAT_NUM + p0 + pq];
        lds[fl*65 + pq + 0] = v.x;
        lds[fl*65 + pq + 1] = v.y;
        lds[fl*65 + pq + 2] = v.z;
        lds[fl*65 + pq + 3] = v.w;
    }
    __syncthreads();
    int fo = (tid & 7)*8, pr = tid >> 3;        // write: lanes contiguous in f
#pragma unroll
    for (int i = 0; i < 2; ++i) {
        int row = pr + i*32;
        ushort vv[8];
#pragma unroll
        for (int j = 0; j < 8; ++j) {
            __hip_bfloat16 b = __float2bfloat16(lds[(fo+j)*65 + row]);
            vv[j] = *(ushort*)&b;
        }
        uint4 pk;
        pk.x = (uint)vv[0] | ((uint)vv[1] << 16);
        pk.y = (uint)vv[2] | ((uint)vv[3] << 16);
        pk.z = (uint)vv[4] | ((uint)vv[5] << 16);
        pk.w = (uint)vv[6] | ((uint)vv[7] << 16);
        *(uint4*)(spT + ((size_t)z*FEAT_NUM + p0 + row)*FEAT_LEN + f0 + fo) = pk;
    }
}

// ---- fast gather + fused border: token reads from spT, NHWC writes to cat ----
// Blocks 0..144 additionally zero the 1-px border (one fewer kernel launch).
__global__ __launch_bounds__(256) void k_gather2(const ushort* __restrict__ spT,
                                                 const float* __restrict__ loc,
                                                 const int* __restrict__ corr_index,
                                                 ushort* __restrict__ cat) {
    __shared__ ushort tok[3*FEAT_LEN];           // 12 KB
    int p = blockIdx.x;
    int y4 = p / W4, x4 = p - y4*W4;
    int tid = threadIdx.x;
    int k = corr_index[p];
    int iy, ix, valid;
    sample_loc(loc, k, p, iy, ix, valid);
    int sp = iy*W4 + ix;

    // fused border zeroing (772 border px * 48 octs = 37056 jobs)
    {
        int job = p*256 + tid;
        if (job < 772*48) {
            int oct = job % 48, bp = job / 48;
            int ypad, xpad;
            if (bp < 194)      { ypad = 0;        xpad = bp; }
            else if (bp < 388) { ypad = 193;      xpad = bp - 194; }
            else if (bp < 580) { ypad = bp - 387; xpad = 0; }
            else               { ypad = bp - 579; xpad = 193; }
            uint4 z = {0u,0u,0u,0u};
            *(uint4*)(cat + ((size_t)ypad*PPX + xpad)*NCH + oct*8) = z;
        }
    }

#pragma unroll
    for (int j = 0; j < 3; ++j) {
        int idx = j*256 + tid;                   // 768 uint4 = 3 sets x 2048 bf16
        int set = idx >> 8, off = (idx & 255)*8;
        uint4 v = {0u,0u,0u,0u};
        if (valid)
            v = *(const uint4*)(spT + ((size_t)(set*4 + k)*FEAT_NUM + sp)*FEAT_LEN + off);
        *(uint4*)(tok + set*FEAT_LEN + off) = v;
    }
    __syncthreads();

#pragma unroll
    for (int j = 0; j < 3; ++j) {
        int idx = j*256 + tid;                   // 16 px x 48 octs
        int px16 = idx / 48, oct = idx - px16*48;
        int ky = px16 >> 2, kx = px16 & 3;
        int y = y4*4 + ky, x = x4*4 + kx;
        int set = oct >> 4, c0 = (oct & 15)*8;
        int sub = (ky << 2) + kx;
        ushort vv[8];
#pragma unroll
        for (int e = 0; e < 8; ++e) vv[e] = tok[set*FEAT_LEN + ((c0 + e) << 4) + sub];
        uint4 pk;
        pk.x = (uint)vv[0] | ((uint)vv[1] << 16);
        pk.y = (uint)vv[2] | ((uint)vv[3] << 16);
        pk.z = (uint)vv[4] | ((uint)vv[5] << 16);
        pk.w = (uint)vv[6] | ((uint)vv[7] << 16);
        *(uint4*)(cat + ((size_t)(y+1)*PPX + (x+1))*NCH + set*128 + c0) = pk;
    }
}

// ---- fast correlation: contiguous token reads from idxT ----
__global__ __launch_bounds__(256) void k_corr2(const float* __restrict__ curr,
                                               const float* __restrict__ idxT,
                                               const float* __restrict__ loc,
                                               int* __restrict__ corr_index,
                                               float* __restrict__ corr_soft) {
    int p = blockIdx.x;
    int y4 = p / W4, x4 = p - y4*W4;
    int tid = threadIdx.x;

    int iy[T_FRAMES], ix[T_FRAMES], valid[T_FRAMES];
    const float* tok[T_FRAMES];
#pragma unroll
    for (int k = 0; k < T_FRAMES; ++k) {
        sample_loc(loc, k, p, iy[k], ix[k], valid[k]);
        tok[k] = idxT + ((size_t)k*FEAT_NUM + iy[k]*W4 + ix[k])*FEAT_LEN;
    }

    float ss_cf = 0.f;
    float dotk[T_FRAMES] = {0.f,0.f,0.f,0.f};
    float ssk[T_FRAMES]  = {0.f,0.f,0.f,0.f};
    int ybase = y4*4, xbase = x4*4;

#pragma unroll
    for (int it = 0; it < 2; ++it) {
        int f4 = (tid + it*256)*4;
        int cc = f4 >> 4, kh = (f4 >> 2) & 3;
        float4 cf = *(const float4*)&curr[cc*HW + (ybase+kh)*W + xbase];
        ss_cf += cf.x*cf.x + cf.y*cf.y + cf.z*cf.z + cf.w*cf.w;
#pragma unroll
        for (int k = 0; k < T_FRAMES; ++k) {
            if (valid[k]) {
                float4 v = *(const float4*)&tok[k][f4];
                dotk[k] += cf.x*v.x + cf.y*v.y + cf.z*v.z + cf.w*v.w;
                ssk[k]  += v.x*v.x + v.y*v.y + v.z*v.z + v.w*v.w;
            }
        }
    }

    float vals[9] = {ss_cf, dotk[0],dotk[1],dotk[2],dotk[3], ssk[0],ssk[1],ssk[2],ssk[3]};
#pragma unroll
    for (int j = 0; j < 9; ++j) {
        float v = vals[j];
#pragma unroll
        for (int off = 32; off > 0; off >>= 1) v += __shfl_xor(v, off, 64);
        vals[j] = v;
    }
    __shared__ float red[4][9];
    int wave = tid >> 6, lane = tid & 63;
    if (lane == 0) {
#pragma unroll
        for (int j = 0; j < 9; ++j) red[wave][j] = vals[j];
    }
    __syncthreads();
    if (tid == 0) {
        float tot[9];
#pragma unroll
        for (int j = 0; j < 9; ++j) tot[j] = red[0][j]+red[1][j]+red[2][j]+red[3][j];
        float ncf = fmaxf(sqrtf(tot[0]), 1e-12f);
        float best = -1e30f; int bestk = 0;
#pragma unroll
        for (int k = 0; k < T_FRAMES; ++k) {
            float nk = fmaxf(sqrtf(tot[5+k]), 1e-12f);
            float m = tot[1+k] / (nk * ncf);
            if (m > best) { best = m; bestk = k; }   // strict > == first-max
        }
        corr_index[p] = bestk;
        corr_soft[p]  = best;
    }
}

// ---- fallback correlation (strided reads) if ws too small for idxT ----
__global__ __launch_bounds__(256) void k_corr(const float* __restrict__ curr,
                                              const float* __restrict__ idxf,
                                              const float* __restrict__ loc,
                                              int* __restrict__ corr_index,
                                              float* __restrict__ corr_soft) {
    int p = blockIdx.x;
    int y4 = p / W4, x4 = p - y4*W4;
    int tid = threadIdx.x;

    int iy[T_FRAMES], ix[T_FRAMES], valid[T_FRAMES];
#pragma unroll
    for (int k = 0; k < T_FRAMES; ++k) sample_loc(loc, k, p, iy[k], ix[k], valid[k]);

    float ss_cf = 0.f;
    float dotk[T_FRAMES] = {0.f,0.f,0.f,0.f};
    float ssk[T_FRAMES]  = {0.f,0.f,0.f,0.f};

    int ybase = y4*4, xbase = x4*4;
    for (int f = tid; f < FEAT_LEN; f += 256) {
        int cc = f >> 4;
        int kh = (f >> 2) & 3;
        int kw = f & 3;
        float cf = curr[cc*HW + (ybase+kh)*W + (xbase+kw)];
        ss_cf += cf*cf;
#pragma unroll
        for (int k = 0; k < T_FRAMES; ++k) {
            float v = 0.f;
            if (valid[k]) v = idxf[(k*FEAT_LEN + f)*FEAT_NUM + iy[k]*W4 + ix[k]];
            dotk[k] += cf*v;
            ssk[k]  += v*v;
        }
    }

    float vals[9] = {ss_cf, dotk[0],dotk[1],dotk[2],dotk[3], ssk[0],ssk[1],ssk[2],ssk[3]};
#pragma unroll
    for (int j = 0; j < 9; ++j) {
        float v = vals[j];
#pragma unroll
        for (int off = 32; off > 0; off >>= 1) v += __shfl_xor(v, off, 64);
        vals[j] = v;
    }
    __shared__ float red[4][9];
    int wave = tid >> 6, lane = tid & 63;
    if (lane == 0) {
#pragma unroll
        for (int j = 0; j < 9; ++j) red[wave][j] = vals[j];
    }
    __syncthreads();
    if (tid == 0) {
        float tot[9];
#pragma unroll
        for (int j = 0; j < 9; ++j) tot[j] = red[0][j]+red[1][j]+red[2][j]+red[3][j];
        float ncf = fmaxf(sqrtf(tot[0]), 1e-12f);
        float best = -1e30f; int bestk = 0;
#pragma unroll
        for (int k = 0; k < T_FRAMES; ++k) {
            float nk = fmaxf(sqrtf(tot[5+k]), 1e-12f);
            float m = tot[1+k] / (nk * ncf);
            if (m > best) { best = m; bestk = k; }
        }
        corr_index[p] = bestk;
        corr_soft[p]  = best;
    }
}

// ---- weights fp32 OIHW -> bf16 MFMA-fragment order ----
// wt2[(((step*2 + kk)*8 + g)*64 + lane)*8 + e]
__global__ __launch_bounds__(256) void k_wconv(const float* __restrict__ w,
                                               ushort* __restrict__ wt2) {
    int gid = blockIdx.x*256 + threadIdx.x;
    if (gid >= 128*KTOT) return;
    int e  = gid & 7;
    int l  = (gid >> 3) & 63;
    int g  = (gid >> 9) & 7;
    int kkstep = gid >> 12;          // 0..107
    int kk = kkstep & 1, step = kkstep >> 1;
    int lx = l & 15, lg = l >> 4;
    int col = g*16 + lx;
    int chunk = step / 9, tap = step - chunk*9;
    int ci = chunk*64 + kk*32 + lg*8 + e;
    __hip_bfloat16 b = __float2bfloat16(w[(col*NCH + ci)*9 + tap]);
    wt2[gid] = *(ushort*)&b;
}

// ---- border kernel (fallback path only) ----
__global__ __launch_bounds__(256) void k_border(ushort* __restrict__ cat) {
    int gid = blockIdx.x*256 + threadIdx.x;
    if (gid >= 772*48) return;
    int oct = gid % 48, bp = gid / 48;
    int ypad, xpad;
    if (bp < 194)      { ypad = 0;        xpad = bp; }
    else if (bp < 388) { ypad = 193;      xpad = bp - 194; }
    else if (bp < 580) { ypad = bp - 387; xpad = 0; }
    else               { ypad = bp - 579; xpad = 193; }
    uint4 z = {0u,0u,0u,0u};
    *(uint4*)(cat + (ypad*PPX + xpad)*NCH + oct*8) = z;
}

// ---- fallback gather (strided reads) ----
__global__ __launch_bounds__(256) void k_gather(const float* __restrict__ s1,
                                                const float* __restrict__ s2,
                                                const float* __restrict__ s3,
                                                const float* __restrict__ loc,
                                                const int* __restrict__ corr_index,
                                                ushort* __restrict__ cat) {
    int gid = blockIdx.x*256 + threadIdx.x;
    if (gid >= HW*48) return;
    int oct = gid % 48, px = gid / 48;
    int x = px % W, y = px / W;
    int p = (y >> 2)*W4 + (x >> 2);
    int k = corr_index[p];
    int iy, ix, valid;
    sample_loc(loc, k, p, iy, ix, valid);
    int set = oct >> 4;
    int c0  = (oct & 15) * 8;
    int sub = ((y & 3) << 2) + (x & 3);
    ushort v[8];
#pragma unroll
    for (int e = 0; e < 8; ++e) v[e] = 0;
    if (valid) {
        const float* src = (set == 0) ? s1 : ((set == 1) ? s2 : s3);
        const float* sp = src + (size_t)k*FEAT_LEN*FEAT_NUM + iy*W4 + ix;
#pragma unroll
        for (int e = 0; e < 8; ++e) {
            int f = ((c0 + e) << 4) + sub;
            __hip_bfloat16 b = __float2bfloat16(sp[(size_t)f*FEAT_NUM]);
            v[e] = *(ushort*)&b;
        }
    }
    uint4 pk;
    pk.x = (uint)v[0] | ((uint)v[1] << 16);
    pk.y = (uint)v[2] | ((uint)v[3] << 16);
    pk.z = (uint)v[4] | ((uint)v[5] << 16);
    pk.w = (uint)v[6] | ((uint)v[7] << 16);
    *(uint4*)(cat + ((y+1)*PPX + (x+1))*NCH + oct*8) = pk;
}

// ---- MFMA implicit-GEMM conv 3x3 384->128: round-10 best geometry ----
// 4 waves x (64px x 32co) — r13 proved halving the wave tile (8-wave) hurts:
// same W-loads feed half the MFMAs. r9 proved (256,4) VGPR-cap spills acc.
// Keep (256,2), coalesced fragment-ordered W, X double-buffer, 6 barriers.
__global__ __launch_bounds__(256, 2) void k_conv2(const ushort* __restrict__ cat,
                                                  const ushort* __restrict__ wt2,
                                                  const float* __restrict__ bias,
                                                  const float* __restrict__ corr_soft,
                                                  const float* __restrict__ anchor,
                                                  float* __restrict__ out) {
    __shared__ char smX[2][136*128];   // [rc=r*34+xp][64 ci * 2B], swizzled

    int tx = blockIdx.x, ty = blockIdx.y;       // 6 x 96
    int tid = threadIdx.x;
    int wave = tid >> 6, l = tid & 63;
    int lx = l & 15, lg = l >> 4;
    int co0w = wave * 32;
    int wbofs = (wave*64)*16;

    auto stageX = [&](int chunk, int b) {
        char* xb = (char*)smX[b];
#pragma unroll
        for (int q = 0; q < 4; ++q) {
            int idx = tid + q*256;
            int rc = idx >> 3, oct = idx & 7;
            int r = rc / 34, xp = rc - r*34;
            int octp = oct ^ (xp & 7);          // pre-swizzle source (rule #21)
            const ushort* gp = cat + ((size_t)(ty*2 + r)*PPX + (tx*32 + xp))*NCH
                               + chunk*64 + octp*8;
            gl16(gp, xb + q*256*16 + wbofs);
        }
        if (wave == 0) {                        // idx 1024..1087 (rc 128..135, r=3)
            int idx = 1024 + l;
            int rc = idx >> 3, oct = idx & 7;
            int xp = rc - 102;                  // r = 3
            int octp = oct ^ (xp & 7);
            const ushort* gp = cat + ((size_t)(ty*2 + 3)*PPX + (tx*32 + xp))*NCH
                               + chunk*64 + octp*8;
            gl16(gp, xb + 1024*16);
        }
    };

    f32x4 acc[2][4];
#pragma unroll
    for (int mf = 0; mf < 2; ++mf)
#pragma unroll
        for (int nf = 0; nf < 4; ++nf) acc[mf][nf] = (f32x4){0.f,0.f,0.f,0.f};

    int pyv[4], pxxv[4];
#pragma unroll
    for (int nf = 0; nf < 4; ++nf) { int pxl = nf*16 + lx; pyv[nf] = pxl >> 5; pxxv[nf] = pxl & 31; }
    const ushort* wfb[2];
#pragma unroll
    for (int mf = 0; mf < 2; ++mf)
        wfb[mf] = wt2 + ((wave*2 + mf)*64 + l)*8;

    stageX(0, 0);
    __syncthreads();

    for (int chunk = 0; chunk < 6; ++chunk) {
        if (chunk < 5) stageX(chunk+1, (chunk+1) & 1);
        const char* Xb = smX[chunk & 1];
#pragma unroll
        for (int tap = 0; tap < 9; ++tap) {
            const int step = chunk*9 + tap;
            const int dy = tap/3 - 1, dx = tap%3 - 1;
            bf16x8 wf[2][2];
#pragma unroll
            for (int mf = 0; mf < 2; ++mf)
#pragma unroll
                for (int kk = 0; kk < 2; ++kk)
                    wf[mf][kk] = *(const bf16x8*)(wfb[mf] + (size_t)(step*2 + kk)*4096);
            int xrc[4], xsw[4];
#pragma unroll
            for (int nf = 0; nf < 4; ++nf) {
                int xp2 = pxxv[nf] + dx + 1;
                xrc[nf] = (pyv[nf] + dy + 1)*34 + xp2;
                xsw[nf] = (xp2 & 7) << 4;
            }
#pragma unroll
            for (int kk = 0; kk < 2; ++kk) {
                int kb = kk*64 + lg*16;
                bf16x8 xf[4];
#pragma unroll
                for (int nf = 0; nf < 4; ++nf)
                    xf[nf] = *(const bf16x8*)(Xb + xrc[nf]*128 + (kb ^ xsw[nf]));
#pragma unroll
                for (int mf = 0; mf < 2; ++mf)
#pragma unroll
                    for (int nf = 0; nf < 4; ++nf)
                        acc[mf][nf] = __builtin_amdgcn_mfma_f32_16x16x32_bf16(
                            wf[mf][kk], xf[nf], acc[mf][nf], 0, 0, 0);
            }
        }
        __syncthreads();
    }

    float cs[4]; int pixo[4];
#pragma unroll
    for (int nf = 0; nf < 4; ++nf) {
        int y = ty*2 + pyv[nf];
        int x = tx*32 + pxxv[nf];
        cs[nf] = corr_soft[(ty >> 1)*W4 + (x >> 2)];
        pixo[nf] = y*W + x;
    }
#pragma unroll
    for (int mf = 0; mf < 2; ++mf) {
#pragma unroll
        for (int j = 0; j < 4; ++j) {
            int co = co0w + mf*16 + lg*4 + j;
            float b = bias[co];
#pragma unroll
            for (int nf = 0; nf < 4; ++nf) {
                int o = co*HW + pixo[nf];
                out[o] = (acc[mf][nf][j] + b)*cs[nf] + anchor[o];
            }
        }
    }
}

extern "C" void kernel_launch(void* const* d_in, const int* in_sizes, int n_in,
                              void* d_out, int out_size, void* d_ws, size_t ws_size,
                              hipStream_t stream) {
    const float* curr   = (const float*)d_in[0];
    const float* idxf   = (const float*)d_in[1];
    const float* anchor = (const float*)d_in[2];
    const float* s1     = (const float*)d_in[3];
    const float* s2     = (const float*)d_in[4];
    const float* s3     = (const float*)d_in[5];
    const float* loc    = (const float*)d_in[6];
    const float* wgt    = (const float*)d_in[7];
    const float* bias   = (const float*)d_in[8];
    float* out = (float*)d_out;

    char* ws = (char*)d_ws;
    int*    corr_index = (int*)ws;                   // 2304 i32
    float*  corr_soft  = (float*)(ws + 16384);       // 2304 f32
    ushort* wt2        = (ushort*)(ws + 32768);      // 884,736 B (fragment order)
    ushort* cat        = (ushort*)(ws + 917504);     // 28,912,128 B
    // BIG region: idxT (75.5 MB fp32, corr phase) then spT (113.2 MB bf16,
    // gather phase) alias each other — lifetimes disjoint, stream-ordered.
    char*   big        = ws + 917504 + 28912128;     // offset 29,829,632
    float*  idxT       = (float*)big;
    ushort* spT        = (ushort*)big;
    const size_t SPT_BYTES  = (size_t)3*T_FRAMES*FEAT_NUM*FEAT_LEN*2;  // 113,246,208
    const size_t IDXT_BYTES = (size_t)T_FRAMES*FEAT_NUM*FEAT_LEN*4;    //  75,497,472
    const size_t NEED_A = 29829632 + (SPT_BYTES > IDXT_BYTES ? SPT_BYTES : IDXT_BYTES);
    const size_t NEED_B = 917504 + IDXT_BYTES;

    if (ws_size >= NEED_A) {
        hipLaunchKernelGGL(k_tr, dim3(36, 32, 4), dim3(256), 0, stream, idxf, idxT);
        hipLaunchKernelGGL(k_corr2, dim3(FEAT_NUM), dim3(256), 0, stream,
                           curr, idxT, loc, corr_index, corr_soft);
        hipLaunchKernelGGL(k_wconv, dim3((128*KTOT + 255)/256), dim3(256), 0, stream, wgt, wt2);
        hipLaunchKernelGGL(k_trs, dim3(36, 32, 12), dim3(256), 0, stream, s1, s2, s3, spT);
        hipLaunchKernelGGL(k_gather2, dim3(FEAT_NUM), dim3(256), 0, stream,
                           spT, loc, corr_index, cat);   // border fused in
    } else {
        float*  idxT_b = (float*)(ws + 917504);
        ushort* cat_b  = (ushort*)(ws + 917504);
        if (ws_size >= NEED_B) {
            hipLaunchKernelGGL(k_tr, dim3(36, 32, 4), dim3(256), 0, stream, idxf, idxT_b);
            hipLaunchKernelGGL(k_corr2, dim3(FEAT_NUM), dim3(256), 0, stream,
                               curr, idxT_b, loc, corr_index, corr_soft);
        } else {
            hipLaunchKernelGGL(k_corr, dim3(FEAT_NUM), dim3(256), 0, stream,
                               curr, idxf, loc, corr_index, corr_soft);
        }
        hipLaunchKernelGGL(k_wconv, dim3((128*KTOT + 255)/256), dim3(256), 0, stream, wgt, wt2);
        hipLaunchKernelGGL(k_border, dim3((772*48 + 255)/256), dim3(256), 0, stream, cat_b);
        hipLaunchKernelGGL(k_gather, dim3((HW*48 + 255)/256), dim3(256), 0, stream,
                           s1, s2, s3, loc, corr_index, cat_b);
        hipLaunchKernelGGL(k_conv2, dim3(6, 96), dim3(256), 0, stream,
                           cat_b, wt2, bias, corr_soft, anchor, out);
        return;
    }
    hipLaunchKernelGGL(k_conv2, dim3(6, 96), dim3(256), 0, stream,
                       cat, wt2, bias, corr_soft, anchor, out);
}